// Round 1
// baseline (5649.479 us; speedup 1.0000x reference)
//
#include <hip/hip_runtime.h>

#define C512 512

// Kt[((pq)*512 + a)*512 + b] = K[(a*512+b)*9 + pq]
// Serves BOTH as the GEMM A operand (A_pq[o][c]) and as step-2's B operand
// (B_uv[c][i]), since both are just K[a][b][·][·] reindexed spatial-major.
__global__ void k_transform(const float* __restrict__ K, float* __restrict__ Kt) {
    int t = blockIdx.x * blockDim.x + threadIdx.x; // a*512 + b
    if (t >= C512 * C512) return;
    float v[9];
#pragma unroll
    for (int j = 0; j < 9; ++j) v[j] = K[(long long)t * 9 + j];
#pragma unroll
    for (int j = 0; j < 9; ++j) Kt[((long long)j * C512 * C512) + t] = v[j];
}

// kg[o][i][11][11] = centered K (at rows/cols 4..6) + identity at (5,5)
__global__ void k_init(const float* __restrict__ K, float* __restrict__ kg) {
    long long t = (long long)blockIdx.x * blockDim.x + threadIdx.x;
    const long long total = (long long)C512 * C512 * 121;
    if (t >= total) return;
    int yx = (int)(t % 121);
    long long oi = t / 121;
    int i = (int)(oi & 511);
    int o = (int)(oi >> 9);
    int y = yx / 11, x = yx % 11;
    float v = 0.f;
    int p = y - 4, q = x - 4;
    if (p >= 0 && p < 3 && q >= 0 && q < 3) v = K[oi * 9 + p * 3 + q];
    if (o == i && y == 5 && x == 5) v += 1.f;
    kg[t] = v;
}

// One GEMM per output spatial position (y,x) of the composed kernel:
//   C_yx[o,i] = alpha * sum_{valid p,q} sum_c A[pq][o][c] * B[u*s_in+v][c][i]
// with u=y-p, v=x-q. Writes Ki_t (layout [yx][o][i]) and accumulates into kg.
__global__ __launch_bounds__(256)
void k_gemm(const float* __restrict__ A,   // Kt: [9][512][512]
            const float* __restrict__ B,   // [s_in^2][512][512]
            float* __restrict__ ki_out,    // [s_out^2][512][512] or null
            float* __restrict__ kg,        // [512][512][11][11]
            int s_in, int s_out, int ofs, float alpha, int write_ki)
{
    __shared__ float As[16][68]; // padded: transposed store, 2-way max conflict
    __shared__ float Bs[16][64];

    int yx = blockIdx.z;
    int y = yx / s_out, x = yx % s_out;
    int o0 = blockIdx.y * 64;
    int i0 = blockIdx.x * 64;
    int tid = threadIdx.x;
    int tx = tid & 15, ty = tid >> 4;

    float acc[4][4] = {};

    // A tile load mapping: 64 rows(o) x 16 cols(c), float4 per thread
    int a_or = tid >> 2, a_cr = (tid & 3) * 4;
    // B tile load mapping: 16 rows(c) x 64 cols(i), float4 per thread
    int b_cr = tid >> 4, b_ir = (tid & 15) * 4;

    for (int pq = 0; pq < 9; ++pq) {
        int p = pq / 3, q = pq % 3;
        int u = y - p, v = x - q;
        if (u < 0 || u >= s_in || v < 0 || v >= s_in) continue; // uniform skip
        const float* Ap = A + ((long long)pq * C512 + o0) * C512;
        const float* Bp = B + (long long)(u * s_in + v) * C512 * C512 + i0;
        for (int c0 = 0; c0 < C512; c0 += 16) {
            float4 av = *(const float4*)(Ap + (long long)a_or * C512 + c0 + a_cr);
            float4 bv = *(const float4*)(Bp + (long long)(c0 + b_cr) * C512 + b_ir);
            As[a_cr + 0][a_or] = av.x;
            As[a_cr + 1][a_or] = av.y;
            As[a_cr + 2][a_or] = av.z;
            As[a_cr + 3][a_or] = av.w;
            *(float4*)&Bs[b_cr][b_ir] = bv;
            __syncthreads();
#pragma unroll
            for (int k = 0; k < 16; ++k) {
                float4 a4 = *(const float4*)&As[k][ty * 4];
                float4 b4 = *(const float4*)&Bs[k][tx * 4];
                float am[4] = {a4.x, a4.y, a4.z, a4.w};
                float bn[4] = {b4.x, b4.y, b4.z, b4.w};
#pragma unroll
                for (int m = 0; m < 4; ++m)
#pragma unroll
                    for (int n = 0; n < 4; ++n)
                        acc[m][n] += am[m] * bn[n];
            }
            __syncthreads();
        }
    }

    int om = o0 + ty * 4, in = i0 + tx * 4;
#pragma unroll
    for (int m = 0; m < 4; ++m) {
        float4 st = make_float4(acc[m][0] * alpha, acc[m][1] * alpha,
                                acc[m][2] * alpha, acc[m][3] * alpha);
        if (write_ki) {
            *(float4*)(ki_out + ((long long)yx * C512 + (om + m)) * C512 + in) = st;
        }
        // accumulate into kg at [o][i][ofs+y][ofs+x] (scattered fp32 RMW)
        float vs[4] = {st.x, st.y, st.z, st.w};
#pragma unroll
        for (int n = 0; n < 4; ++n) {
            long long idx = ((long long)(om + m) * C512 + (in + n)) * 121
                          + (ofs + y) * 11 + (ofs + x);
            kg[idx] += vs[n];
        }
    }
}

extern "C" void kernel_launch(void* const* d_in, const int* in_sizes, int n_in,
                              void* d_out, int out_size, void* d_ws, size_t ws_size,
                              hipStream_t stream) {
    const float* K = (const float*)d_in[0];
    float* kg = (float*)d_out;
    char* ws = (char*)d_ws;

    // ws layout (fp32): Kt 9.4MB | bufA 85MB (Ki2 then Ki4) | bufB 51MB (Ki3)
    float* Kt   = (float*)(ws);
    float* bufA = (float*)(ws + (size_t)9437184);
    float* bufB = (float*)(ws + (size_t)9437184 + (size_t)84934656);

    k_transform<<<(C512 * C512 + 255) / 256, 256, 0, stream>>>(K, Kt);
    k_init<<<(int)(((long long)C512 * C512 * 121 + 255) / 256), 256, 0, stream>>>(K, kg);

    // step t=2: Ki2 = (K*K)/2   : B=Kt  (3x3) -> bufA (5x5),  ofs=3
    k_gemm<<<dim3(8, 8, 25), 256, 0, stream>>>(Kt, Kt, bufA, kg, 3, 5, 3, 0.5f, 1);
    // step t=3: Ki3 = (K*Ki2)/3 : bufA (5x5) -> bufB (7x7),  ofs=2
    k_gemm<<<dim3(8, 8, 49), 256, 0, stream>>>(Kt, bufA, bufB, kg, 5, 7, 2, 1.f / 3.f, 1);
    // step t=4: Ki4 = (K*Ki3)/4 : bufB (7x7) -> bufA (9x9),  ofs=1
    k_gemm<<<dim3(8, 8, 81), 256, 0, stream>>>(Kt, bufB, bufA, kg, 7, 9, 1, 0.25f, 1);
    // step t=5: Ki5 = (K*Ki4)/5 : bufA (9x9) -> kg only (11x11), ofs=0
    k_gemm<<<dim3(8, 8, 121), 256, 0, stream>>>(Kt, bufA, nullptr, kg, 9, 11, 0, 0.2f, 0);
}

// Round 2
// 762.351 us; speedup vs baseline: 7.4106x; 7.4106x over previous
//
#include <hip/hip_runtime.h>
#include <stdint.h>

#define C 512
#define C2 262144  // 512*512

typedef __attribute__((ext_vector_type(8))) short bf16x8;
typedef __attribute__((ext_vector_type(4))) float f32x4;

__device__ __forceinline__ unsigned short f2bf(float f) {
    union { float f; uint32_t u; } v; v.f = f;
    uint32_t u = v.u;
    u += 0x7fffu + ((u >> 16) & 1u);   // round-to-nearest-even
    return (unsigned short)(u >> 16);
}
__device__ __forceinline__ float bf2f(unsigned short h) {
    union { uint32_t u; float f; } v; v.u = ((uint32_t)h) << 16;
    return v.f;
}

#define GL2LDS16(g, l) __builtin_amdgcn_global_load_lds( \
    (const __attribute__((address_space(1))) void*)(g),  \
    (__attribute__((address_space(3))) void*)(l), 16, 0, 0)

// K [o][i][3][3] fp32 ->
//   Kt  bf16 [j][o][c] = K[o][c][j]   (GEMM B operand, rows o, contiguous c)
//   KtT bf16 [j][i][c] = K[c][i][j]   (step-2 GEMM A operand = Ki1^T)
//   Ktf f32  [j][i][o] = K[o][i][j]   (assembly K-term, coalesced in o)
__global__ void k_transform(const float* __restrict__ K,
                            unsigned short* __restrict__ Kt,
                            unsigned short* __restrict__ KtT,
                            float* __restrict__ Ktf) {
    int t = blockIdx.x * 256 + threadIdx.x;  // t = a*512 + b
    int a = t >> 9, b = t & 511;
#pragma unroll
    for (int j = 0; j < 9; ++j) {
        float v = K[(size_t)t * 9 + j];          // K[a][b][j]
        unsigned short h = f2bf(v);
        Kt[(size_t)j * C2 + t] = h;                         // [j][a=o][b=c]
        KtT[(size_t)j * C2 + (size_t)b * C + a] = h;        // [j][b=i][a=c]
        Ktf[(size_t)j * C2 + (size_t)b * C + a] = v;        // [j][b=i][a=o]
    }
}

// Ki_t^T[yx][i][o] = alpha * sum_{pq valid} sum_c A[uv][i][c] * B[pq][o][c]
// A = Ki_{t-1}^T (bf16), B = Kt (bf16). m97 structure: 128x128 tile, BK=32.
__global__ __launch_bounds__(256) void k_gemm(
    const unsigned short* __restrict__ A,   // [s_in^2][512 i][512 c] bf16
    const unsigned short* __restrict__ Bm,  // [9][512 o][512 c] bf16
    unsigned short* __restrict__ Out,       // [s_out^2][512 i][512 o] bf16
    int s_in, int s_out, float alpha)
{
    __shared__ unsigned short As[128 * 32];  // [i_local][c_local] linear
    __shared__ unsigned short Bs[128 * 32];  // [o_local][c_local] linear

    const int tid = threadIdx.x;
    const int lane = tid & 63, wid = tid >> 6;
    const int wr = wid >> 1, wc = wid & 1;       // wave tile 64(i) x 64(o)
    const int i0 = blockIdx.x * 128, o0 = blockIdx.y * 128;
    const int yx = blockIdx.z;
    const int y = yx / s_out, x = yx % s_out;
    const int l15 = lane & 15, lhi = lane >> 4;

    f32x4 acc[4][4] = {};

    // staging: thread t -> tile row t>>2 (and +64), byte col (t&3)*16
    const int sr = tid >> 2;
    const int sbyte = (tid & 3) * 16;
    char* AsB = (char*)As;
    char* BsB = (char*)Bs;
    // fragment element offsets (row*32 + khalf*8), rows stride 64B
    const int aoff = (wr * 64 + l15) * 32 + lhi * 8;
    const int boff = (wc * 64 + l15) * 32 + lhi * 8;

    for (int pq = 0; pq < 9; ++pq) {
        const int u = y - pq / 3, v = x - pq % 3;
        if (u < 0 || u >= s_in || v < 0 || v >= s_in) continue;  // uniform
        const char* Apt = (const char*)(A + ((size_t)(u * s_in + v) * C + i0) * C)
                        + sr * 1024 + sbyte;
        const char* Bpt = (const char*)(Bm + ((size_t)pq * C + o0) * C)
                        + sr * 1024 + sbyte;
        for (int cb = 0; cb < 1024; cb += 64) {   // K-chunk byte offset
            GL2LDS16(Apt + cb,         AsB + tid * 16);
            GL2LDS16(Apt + cb + 65536, AsB + 4096 + tid * 16);
            GL2LDS16(Bpt + cb,         BsB + tid * 16);
            GL2LDS16(Bpt + cb + 65536, BsB + 4096 + tid * 16);
            __syncthreads();
            bf16x8 af[4], bfr[4];
#pragma unroll
            for (int mi = 0; mi < 4; ++mi)
                af[mi] = *(const bf16x8*)(As + aoff + mi * 512);
#pragma unroll
            for (int ni = 0; ni < 4; ++ni)
                bfr[ni] = *(const bf16x8*)(Bs + boff + ni * 512);
#pragma unroll
            for (int mi = 0; mi < 4; ++mi)
#pragma unroll
                for (int ni = 0; ni < 4; ++ni)
                    acc[mi][ni] = __builtin_amdgcn_mfma_f32_16x16x32_bf16(
                        af[mi], bfr[ni], acc[mi][ni], 0, 0, 0);
            __syncthreads();
        }
    }

    // D layout: col(o) = lane&15, row(i) = (lane>>4)*4 + reg
#pragma unroll
    for (int mi = 0; mi < 4; ++mi) {
#pragma unroll
        for (int r = 0; r < 4; ++r) {
            const int irow = i0 + wr * 64 + mi * 16 + lhi * 4 + r;
            unsigned short* op = Out + ((size_t)yx * C + irow) * C
                               + o0 + wc * 64 + l15;
#pragma unroll
            for (int ni = 0; ni < 4; ++ni)
                op[ni * 16] = f2bf(acc[mi][ni][r] * alpha);
        }
    }
}

// Accumulate Ki_t (bf16, [s^2][i][o]) into kg ([o][i][11][11] fp32) at
// centered offset. init=1 also writes K-term + identity and the zeros
// (full 121 window, plain stores -> no kg pre-read).
__global__ __launch_bounds__(256) void k_addki(
    const unsigned short* __restrict__ Ki,
    const float* __restrict__ Ktf,          // [9][i][o] f32
    float* __restrict__ kg,
    int s, int ofs, int init)
{
    __shared__ float L[64 * 121];
    const int i = blockIdx.x;
    const int o0 = blockIdx.y * 64;
    const int tid = threadIdx.x, lane = tid & 63, wid = tid >> 6;
    const int s2 = s * s;

    if (init) {
        for (int idx = tid; idx < 64 * 121; idx += 256) L[idx] = 0.f;
    }
    __syncthreads();

    if (init) {
        for (int yx = wid; yx < s2; yx += 4) {
            float v = bf2f(Ki[((size_t)yx * C + i) * C + o0 + lane]);
            int yy = yx / s + ofs, xx = yx % s + ofs;
            L[lane * 121 + yy * 11 + xx] = v;   // lane owns o_local -> no race
        }
    } else {
        for (int yx = wid; yx < s2; yx += 4) {
            float v = bf2f(Ki[((size_t)yx * C + i) * C + o0 + lane]);
            L[lane * s2 + yx] = v;              // odd stride -> conflict-free
        }
    }
    __syncthreads();

    if (init) {
        for (int j = wid; j < 9; j += 4) {      // K-term at rows/cols 4..6
            float v = Ktf[(size_t)j * C2 + (size_t)i * C + o0 + lane];
            if (j == 4 && (o0 + lane) == i) v += 1.0f;  // identity at (5,5)
            int yy = j / 3 + 4, xx = j % 3 + 4;
            L[lane * 121 + yy * 11 + xx] += v;
        }
    }
    __syncthreads();

    if (init) {
        for (int idx = tid; idx < 64 * 121; idx += 256) {
            int ol = idx / 121, w = idx - ol * 121;
            kg[((size_t)(o0 + ol) * C + i) * 121 + w] = L[idx];
        }
    } else {
        for (int idx = tid; idx < 64 * s2; idx += 256) {
            int ol = idx / s2, w = idx - ol * s2;
            int yy = w / s + ofs, xx = w - (w / s) * s + ofs;
            kg[((size_t)(o0 + ol) * C + i) * 121 + yy * 11 + xx] += L[idx];
        }
    }
}

extern "C" void kernel_launch(void* const* d_in, const int* in_sizes, int n_in,
                              void* d_out, int out_size, void* d_ws, size_t ws_size,
                              hipStream_t stream) {
    const float* K = (const float*)d_in[0];
    float* kg = (float*)d_out;
    char* ws = (char*)d_ws;

    // ws: Kt 4.5MB | KtT 4.5MB | Ktf 9MB | P1 40.5MB (Ki2,Ki4) | P2 60.5MB (Ki3,Ki5)
    unsigned short* Kt  = (unsigned short*)(ws);
    unsigned short* KtT = (unsigned short*)(ws + (size_t)4718592);
    float*          Ktf = (float*)         (ws + (size_t)9437184);
    unsigned short* P1  = (unsigned short*)(ws + (size_t)18874368);
    unsigned short* P2  = (unsigned short*)(ws + (size_t)61341696);
    // total: 124,780,544 bytes

    k_transform<<<1024, 256, 0, stream>>>(K, Kt, KtT, Ktf);

    // t=2: Ki2^T = (K*K)/2          A=KtT(3x3) -> P1 (5x5)
    k_gemm<<<dim3(4, 4, 25), 256, 0, stream>>>(KtT, Kt, P1, 3, 5, 0.5f);
    k_addki<<<dim3(512, 8), 256, 0, stream>>>(P1, Ktf, kg, 5, 3, 1);
    // t=3: Ki3^T = (K*Ki2)/3        A=P1 (5x5) -> P2 (7x7)
    k_gemm<<<dim3(4, 4, 49), 256, 0, stream>>>(P1, Kt, P2, 5, 7, 1.0f / 3.0f);
    k_addki<<<dim3(512, 8), 256, 0, stream>>>(P2, Ktf, kg, 7, 2, 0);
    // t=4: Ki4^T = (K*Ki3)/4        A=P2 (7x7) -> P1 (9x9)
    k_gemm<<<dim3(4, 4, 81), 256, 0, stream>>>(P2, Kt, P1, 7, 9, 0.25f);
    k_addki<<<dim3(512, 8), 256, 0, stream>>>(P1, Ktf, kg, 9, 1, 0);
    // t=5: Ki5^T = (K*Ki4)/5        A=P1 (9x9) -> P2 (11x11)
    k_gemm<<<dim3(4, 4, 121), 256, 0, stream>>>(P1, Kt, P2, 9, 11, 0.2f);
    k_addki<<<dim3(512, 8), 256, 0, stream>>>(P2, Ktf, kg, 11, 0, 0);
}